// Round 1
// 165.153 us; speedup vs baseline: 1.0088x; 1.0088x over previous
//
#include <hip/hip_runtime.h>
#include <math.h>

#define BD 64
#define ND 200
#define CD 8
#define HD 256
#define WD 256
#define HW (HD * WD)
#define NBOX (BD * ND)      // 12800 boxes
#define PBLK (NBOX / 64)    // 200 partial blocks, 1 wave each

__device__ __forceinline__ float softplus_f(float x) {
    // matches jax.nn.softplus: max(x,0) + log1p(exp(-|x|))
    return fmaxf(x, 0.0f) + log1pf(expf(-fabsf(x)));
}

// One thread per box: reads its 5 target floats once, issues 8 independent
// gathered loads (full MLP depth), computes all three loss terms locally.
// One wave per block -> pure shfl reduction, no LDS, no __syncthreads.
__global__ __launch_bounds__(64) void yolo_partial(const float* __restrict__ pred,
                                                   const float* __restrict__ targets,
                                                   float* __restrict__ partial) {
    const int box = blockIdx.x * 64 + threadIdx.x;
    const int b   = box / ND;

    const float* t = targets + (size_t)box * 5;
    const float cls_id = t[0];
    const float c0 = t[1], c1 = t[2], c2 = t[3], c3 = t[4];

    const bool valid = (cls_id >= 0.0f) && ((c0 + c1 + c2 + c3) > 0.0f);
    const int xpix = (int)(c0 * (float)WD);   // trunc == astype(int32) for positive values
    const int ypix = (int)(c1 * (float)HD);
    const bool inb = (xpix >= 0) && (xpix < WD) && (ypix >= 0) && (ypix < HD);

    float bbox = 0.0f, obj = 0.0f, clsl = 0.0f;
    if (valid && inb) {
        const int xs = min(max(xpix, 0), WD - 1);
        const int ys = min(max(ypix, 0), HD - 1);
        const float* p = pred + (size_t)b * CD * HW + (size_t)ys * WD + xs;

        // 8 independent gathers, 256 KB apart (one per channel)
        const float p0 = p[0 * HW], p1 = p[1 * HW], p2 = p[2 * HW], p3 = p[3 * HW];
        const float p4 = p[4 * HW], p5 = p[5 * HW], p6 = p[6 * HW], p7 = p[7 * HW];

        const float d0 = p0 - c0, d1 = p1 - c1, d2 = p2 - c2, d3 = p3 - c3;
        bbox = 0.25f * (d0 * d0 + d1 * d1 + d2 * d2 + d3 * d3);

        obj = softplus_f(p4) - p4;                       // z = 1

        const int ci = (int)cls_id;                      // valid => cls_id in {0,1,2}
        const float psel = (ci == 0) ? p5 : (ci == 1) ? p6 : p7;
        clsl = (softplus_f(p5) + softplus_f(p6) + softplus_f(p7) - psel) * (1.0f / 3.0f);
    }

    // wave(64)-level reduction of the three sums
#pragma unroll
    for (int off = 32; off > 0; off >>= 1) {
        bbox += __shfl_down(bbox, off, 64);
        obj  += __shfl_down(obj,  off, 64);
        clsl += __shfl_down(clsl, off, 64);
    }

    if (threadIdx.x == 0) {
        // SoA layout for coalesced finalize reads
        partial[blockIdx.x]            = bbox;
        partial[PBLK + blockIdx.x]     = obj;
        partial[2 * PBLK + blockIdx.x] = clsl;
    }
}

__global__ __launch_bounds__(64) void yolo_final(const float* __restrict__ partial,
                                                 float* __restrict__ out) {
    const int t = threadIdx.x;
    float tb = 0.0f, to = 0.0f, tc = 0.0f;
#pragma unroll
    for (int i = t; i < PBLK; i += 64) {       // 200/64 -> up to 4 iterations
        tb += partial[i];
        to += partial[PBLK + i];
        tc += partial[2 * PBLK + i];
    }
#pragma unroll
    for (int off = 32; off > 0; off >>= 1) {
        tb += __shfl_down(tb, off, 64);
        to += __shfl_down(to, off, 64);
        tc += __shfl_down(tc, off, 64);
    }
    if (t == 0) {
        out[0] = 0.05f * tb + 1.0f * to + 0.5f * tc;
        out[1] = tb;
        out[2] = to;
        out[3] = tc;
    }
}

extern "C" void kernel_launch(void* const* d_in, const int* in_sizes, int n_in,
                              void* d_out, int out_size, void* d_ws, size_t ws_size,
                              hipStream_t stream) {
    const float* pred    = (const float*)d_in[0];
    const float* targets = (const float*)d_in[1];
    float* out     = (float*)d_out;
    float* partial = (float*)d_ws;  // 3*PBLK floats, fully overwritten every call

    yolo_partial<<<PBLK, 64, 0, stream>>>(pred, targets, partial);
    yolo_final<<<1, 64, 0, stream>>>(partial, out);
}